// Round 2
// baseline (328.432 us; speedup 1.0000x reference)
//
#include <hip/hip_runtime.h>
#include <hip/hip_bf16.h>
#include <stdint.h>

#define NTOK 2048
#define NE 64
#define TOPK 4
#define DM 512
#define DF 2048
#define TOTSLOT (NTOK*TOPK)   // 8192

// GEMM tile config: one 192-row M-tile per expert covers counts up to 192
// (mean 128, sigma ~11). Worst case handled by MT_MAX tiles w/ early exit.
#define BM 192
#define BN 128
#define BK 64
#define MT_MAX 11             // ceil(2048/192)

typedef __bf16 bf16;
typedef __bf16 bf16x8 __attribute__((ext_vector_type(8)));
typedef __bf16 bf16x4 __attribute__((ext_vector_type(4)));
typedef float  f32x4  __attribute__((ext_vector_type(4)));
typedef short  short8 __attribute__((ext_vector_type(8)));

// ---------------- fused routing: top-k + normalize + CSR build ----------------
// Single block, 1024 threads, 2 tokens/thread. counts/scan/fill in LDS.

__global__ __launch_bounds__(1024) void k_routing(
    const float* __restrict__ hw, float* __restrict__ top_w,
    int* __restrict__ tok, int* __restrict__ slot_of, int* __restrict__ offsets_g)
{
  __shared__ int cnt_s[NE], fill_s[NE];
  __shared__ int off_s[NE + 1];
  const int tid = threadIdx.x;
  if (tid < NE) { cnt_s[tid] = 0; fill_s[tid] = 0; }
  __syncthreads();

  int ids[2][TOPK];
  #pragma unroll
  for (int p = 0; p < 2; ++p) {
    const int t = tid + p * 1024;
    const float* r = hw + (size_t)t * NE;
    float rv[NE];
    #pragma unroll
    for (int e = 0; e < NE; ++e) rv[e] = r[e];
    float v[TOPK];
    #pragma unroll
    for (int k = 0; k < TOPK; ++k) {
      float best = -1e30f; int bi = 0;
      #pragma unroll
      for (int e = 0; e < NE; ++e) {
        bool used = false;
        #pragma unroll
        for (int j = 0; j < k; ++j) used |= (ids[p][j] == e);
        if (!used && rv[e] > best) { best = rv[e]; bi = e; }
      }
      v[k] = best; ids[p][k] = bi;
    }
    float den = v[0] + v[1] + v[2] + v[3] + 1e-8f;   // matches ref
    #pragma unroll
    for (int k = 0; k < TOPK; ++k) {
      top_w[t*TOPK + k] = v[k] / den;
      atomicAdd(&cnt_s[ids[p][k]], 1);
    }
  }
  __syncthreads();
  if (tid == 0) {
    int a = 0;
    for (int e = 0; e < NE; ++e) { off_s[e] = a; a += cnt_s[e]; }
    off_s[NE] = a;
  }
  __syncthreads();
  #pragma unroll
  for (int p = 0; p < 2; ++p) {
    const int t = tid + p * 1024;
    #pragma unroll
    for (int k = 0; k < TOPK; ++k) {
      int e = ids[p][k];
      int pos = off_s[e] + atomicAdd(&fill_s[e], 1);
      tok[pos] = t;
      slot_of[t*TOPK + k] = pos;
    }
  }
  if (tid <= NE) offsets_g[tid] = off_s[tid];
}

__global__ void k_xcast(const float* __restrict__ x, bf16* __restrict__ xb) {
  int i = blockIdx.x * blockDim.x + threadIdx.x;   // one float4 per thread
  int base = i * 4;
  if (base >= NTOK * DM) return;
  float4 f = *(const float4*)(x + base);
  bf16x4 o;
  o[0] = (bf16)f.x; o[1] = (bf16)f.y; o[2] = (bf16)f.z; o[3] = (bf16)f.w;
  *(bf16x4*)(xb + base) = o;
}

// ---------------- grouped GEMM (register-prefetch pipelined) ----------------
// PASS 1: A = gathered x_bf16 rows (CSR), B^T = W_in[e] (F x D fp32), K=DM,
//         epilogue silu(acc+bias_in) -> H bf16
// PASS 2: A = H rows (contiguous slots), B^T = W_out[e] (D x F fp32), K=DF,
//         epilogue acc+bias_out -> O fp32 (per-slot)
// LDS layout: [row][64 cols] bf16 with 16B-unit XOR swizzle (unit ^= row&7).
// Pipeline: tile kt+1's global loads are issued right after the post-write
// barrier, so their ~900cyc latency hides under tile kt's 192 MFMAs; the
// vmcnt wait lands in the B-convert after the MFMA cluster.

template<int PASS>
__global__ __launch_bounds__(512) void k_gemm(
    const float* __restrict__ W, const float* __restrict__ bias,
    const bf16* __restrict__ Asrc, const int* __restrict__ tok,
    const int* __restrict__ offsets,
    bf16* __restrict__ Hout, float* __restrict__ Oout)
{
  constexpr int K    = (PASS == 1) ? DM : DF;
  constexpr int NDIM = (PASS == 1) ? DF : DM;
  constexpr int KT   = K / BK;
  constexpr int NOUT = NDIM;

  const int e     = blockIdx.z;
  const int mtile = blockIdx.y;
  const int ntile = blockIdx.x;
  const int off   = offsets[e];
  const int cnt   = offsets[e+1] - off;
  if (mtile * BM >= cnt) return;            // early-exit: uniform per block
  const int rowcount = cnt - mtile * BM;
  const int tid = threadIdx.x;

  __shared__ bf16 As[BM * BK];   // 24 KB
  __shared__ bf16 Bs[BN * BK];   // 16 KB

  // --- A staging map: 3 chunks x (512 thr x 8 bf16) covers 192x64 ---
  const bf16* abase[3]; bool aok[3];
  #pragma unroll
  for (int c = 0; c < 3; ++c) {
    int r = (c * 512 + tid) >> 3;
    aok[c] = (r < rowcount);
    int srcrow;
    if (PASS == 1) srcrow = aok[c] ? tok[off + mtile*BM + r] : 0;
    else           srcrow = min(off + mtile*BM + r, TOTSLOT - 1);
    abase[c] = Asrc + (size_t)srcrow * K + (tid & 7) * 8;
  }
  // --- B staging map: thread -> (row = tid>>2, 16-col segment) ---
  const int brow = tid >> 2;
  const float* bbase = W + (size_t)e * NDIM * K + (size_t)(ntile*BN + brow) * K
                         + (tid & 3) * 16;

  // --- wave / fragment geometry: 8 waves = 4(M) x 2(N), wave tile 48x64 ---
  const int wave = tid >> 6, lane = tid & 63;
  const int wm = wave >> 1, wn = wave & 1;
  const int lrow = lane >> 4, lcol = lane & 15;

  f32x4 acc[3][4];
  #pragma unroll
  for (int i = 0; i < 3; ++i)
    #pragma unroll
    for (int j = 0; j < 4; ++j) acc[i][j] = (f32x4)(0.0f);

  // ---- prologue: load tile 0, convert B ----
  short8 areg[3];
  bf16x8 bp0, bp1;
  {
    #pragma unroll
    for (int c = 0; c < 3; ++c) {
      if (PASS == 2 || aok[c]) areg[c] = *(const short8*)(abase[c]);
      else                     areg[c] = (short8){0,0,0,0,0,0,0,0};
    }
    float4 b0[4];
    #pragma unroll
    for (int q = 0; q < 4; ++q) b0[q] = *(const float4*)(bbase + q*4);
    const float* fv = (const float*)b0;
    #pragma unroll
    for (int q = 0; q < 8; ++q) { bp0[q] = (bf16)fv[q]; bp1[q] = (bf16)fv[q+8]; }
  }

  #pragma unroll 1
  for (int kt = 0; kt < KT; ++kt) {
    __syncthreads();   // previous tile fully consumed
    // write A (swizzled 16B units)
    #pragma unroll
    for (int c = 0; c < 3; ++c) {
      int r = (c * 512 + tid) >> 3;
      int u = tid & 7;
      *(short8*)(&As[r*BK + ((u ^ (r & 7)) * 8)]) = areg[c];
    }
    // write B (two swizzled 16B units)
    {
      int u0 = (tid & 3) * 2;
      *(bf16x8*)(&Bs[brow*BK + (((u0  ) ^ (brow & 7)) * 8)]) = bp0;
      *(bf16x8*)(&Bs[brow*BK + (((u0+1) ^ (brow & 7)) * 8)]) = bp1;
    }
    __syncthreads();   // staging visible

    // ---- issue next tile's global loads (overlap with MFMA below) ----
    const bool more = (kt + 1 < KT);
    short8 an[3]; float4 bn[4];
    if (more) {
      const int k1 = (kt + 1) * BK;
      #pragma unroll
      for (int c = 0; c < 3; ++c) {
        if (PASS == 2 || aok[c]) an[c] = *(const short8*)(abase[c] + k1);
        else                     an[c] = (short8){0,0,0,0,0,0,0,0};
      }
      #pragma unroll
      for (int q = 0; q < 4; ++q) bn[q] = *(const float4*)(bbase + k1 + q*4);
    }

    // ---- compute: 2 MFMA K-subtiles of 32 ----
    #pragma unroll
    for (int ks = 0; ks < 2; ++ks) {
      const int uu = ks*4 + lrow;
      bf16x8 af[3], bfr[4];
      #pragma unroll
      for (int i = 0; i < 3; ++i) {
        int m = wm*48 + i*16 + lcol;
        af[i] = *(const bf16x8*)(&As[m*BK + ((uu ^ (m & 7)) * 8)]);
      }
      #pragma unroll
      for (int j = 0; j < 4; ++j) {
        int n = wn*64 + j*16 + lcol;
        bfr[j] = *(const bf16x8*)(&Bs[n*BK + ((uu ^ (n & 7)) * 8)]);
      }
      #pragma unroll
      for (int i = 0; i < 3; ++i)
        #pragma unroll
        for (int j = 0; j < 4; ++j)
          acc[i][j] = __builtin_amdgcn_mfma_f32_16x16x32_bf16(af[i], bfr[j], acc[i][j], 0, 0, 0);
    }

    // ---- retire prefetch: vmcnt wait lands here, under MFMA latency ----
    if (more) {
      #pragma unroll
      for (int c = 0; c < 3; ++c) areg[c] = an[c];
      const float* fv = (const float*)bn;
      #pragma unroll
      for (int q = 0; q < 8; ++q) { bp0[q] = (bf16)fv[q]; bp1[q] = (bf16)fv[q+8]; }
    }
  }

  // --- epilogue. C/D layout: col = lane&15, row = (lane>>4)*4 + reg ---
  const int slotbase = off + mtile * BM;
  #pragma unroll
  for (int i = 0; i < 3; ++i) {
    const int rbase = wm*48 + i*16 + lrow*4;
    #pragma unroll
    for (int j = 0; j < 4; ++j) {
      const int gcol = ntile*BN + wn*64 + j*16 + lcol;
      const float bv = bias[(size_t)e * NOUT + gcol];
      #pragma unroll
      for (int q = 0; q < 4; ++q) {
        const int r = rbase + q;
        if (r < rowcount) {
          float h = acc[i][j][q] + bv;
          if (PASS == 1) {
            float s = h / (1.0f + __expf(-h));      // silu
            Hout[(size_t)(slotbase + r) * DF + gcol] = (bf16)s;
          } else {
            Oout[(size_t)(slotbase + r) * DM + gcol] = h;
          }
        }
      }
    }
  }
}

// ---------------- combine (deterministic, atomic-free) ----------------

__global__ void k_combine(const float* __restrict__ O, const float* __restrict__ top_w,
                          const int* __restrict__ slot_of, float* __restrict__ out) {
  int i = blockIdx.x * blockDim.x + threadIdx.x;   // one float4 per thread
  if (i >= NTOK * DM / 4) return;
  int t  = i / (DM / 4);
  int d4 = (i % (DM / 4)) * 4;
  float4 s = {0.f, 0.f, 0.f, 0.f};
  #pragma unroll
  for (int k = 0; k < TOPK; ++k) {
    float w = top_w[t*TOPK + k];
    int  sl = slot_of[t*TOPK + k];
    float4 o = *(const float4*)(O + (size_t)sl * DM + d4);
    s.x += w * o.x; s.y += w * o.y; s.z += w * o.z; s.w += w * o.w;
  }
  *(float4*)(out + (size_t)t * DM + d4) = s;
}

// ---------------- launch ----------------

extern "C" void kernel_launch(void* const* d_in, const int* in_sizes, int n_in,
                              void* d_out, int out_size, void* d_ws, size_t ws_size,
                              hipStream_t stream) {
  const float* x        = (const float*)d_in[0];
  const float* hw       = (const float*)d_in[1];
  const float* W_in     = (const float*)d_in[2];
  const float* bias_in  = (const float*)d_in[3];
  const float* W_out    = (const float*)d_in[4];
  const float* bias_out = (const float*)d_in[5];
  float* out = (float*)d_out;

  char* ws = (char*)d_ws;
  int*   offsets = (int*)  (ws + 0);                     // 65 ints
  float* top_w   = (float*)(ws + 1024);                  // 32 KB
  int*   slot_of = (int*)  (ws + 1024 + 32768);          // 32 KB
  int*   tok     = (int*)  (ws + 1024 + 2*32768);        // 32 KB
  bf16*  xb      = (bf16*) (ws + 1024 + 3*32768);        // 2 MB
  size_t o_xb_end = 1024 + 3*32768 + (size_t)NTOK*DM*2;
  bf16*  H       = (bf16*) (ws + o_xb_end);              // 32 MB
  size_t o_H_end  = o_xb_end + (size_t)TOTSLOT*DF*2;
  float* O       = (float*)(ws + o_H_end);               // 16 MB

  k_xcast  <<<(NTOK*DM/4)/256, 256, 0, stream>>>(x, xb);
  k_routing<<<1, 1024, 0, stream>>>(hw, top_w, tok, slot_of, offsets);

  dim3 g1(DF/BN, MT_MAX, NE);   // (16, 11, 64)
  k_gemm<1><<<g1, 512, 0, stream>>>(W_in, bias_in, xb, tok, offsets, H, nullptr);
  dim3 g2(DM/BN, MT_MAX, NE);   // (4, 11, 64)
  k_gemm<2><<<g2, 512, 0, stream>>>(W_out, bias_out, H, nullptr, offsets, nullptr, O);

  k_combine<<<(NTOK*DM/4)/256, 256, 0, stream>>>(O, top_w, slot_of, out);
}

// Round 3
// 253.407 us; speedup vs baseline: 1.2961x; 1.2961x over previous
//
#include <hip/hip_runtime.h>
#include <hip/hip_bf16.h>
#include <stdint.h>

#define NTOK 2048
#define NE 64
#define TOPK 4
#define DM 512
#define DF 2048
#define TOTSLOT (NTOK*TOPK)   // 8192

#define BM 192
#define BN 128
#define BK 64
#define MT_MAX 11             // ceil(2048/192)

typedef __bf16 bf16;
typedef __bf16 bf16x8 __attribute__((ext_vector_type(8)));
typedef __bf16 bf16x4 __attribute__((ext_vector_type(4)));
typedef float  f32x4  __attribute__((ext_vector_type(4)));

#define GLD_LDS16(g, l) __builtin_amdgcn_global_load_lds( \
    (const __attribute__((address_space(1))) void*)(g),   \
    (__attribute__((address_space(3))) void*)(l), 16, 0, 0)

// ---------------- fused routing: top-k + normalize + CSR build ----------------

__global__ __launch_bounds__(1024) void k_routing(
    const float* __restrict__ hw, float* __restrict__ top_w,
    int* __restrict__ tok, int* __restrict__ slot_of, int* __restrict__ offsets_g)
{
  __shared__ int cnt_s[NE], fill_s[NE];
  __shared__ int off_s[NE + 1];
  const int tid = threadIdx.x;
  if (tid < NE) { cnt_s[tid] = 0; fill_s[tid] = 0; }
  __syncthreads();

  int ids[2][TOPK];
  #pragma unroll
  for (int p = 0; p < 2; ++p) {
    const int t = tid + p * 1024;
    const float* r = hw + (size_t)t * NE;
    float rv[NE];
    #pragma unroll
    for (int e = 0; e < NE; ++e) rv[e] = r[e];
    float v[TOPK];
    #pragma unroll
    for (int k = 0; k < TOPK; ++k) {
      float best = -1e30f; int bi = 0;
      #pragma unroll
      for (int e = 0; e < NE; ++e) {
        bool used = false;
        #pragma unroll
        for (int j = 0; j < k; ++j) used |= (ids[p][j] == e);
        if (!used && rv[e] > best) { best = rv[e]; bi = e; }
      }
      v[k] = best; ids[p][k] = bi;
    }
    float den = v[0] + v[1] + v[2] + v[3] + 1e-8f;
    #pragma unroll
    for (int k = 0; k < TOPK; ++k) {
      top_w[t*TOPK + k] = v[k] / den;
      atomicAdd(&cnt_s[ids[p][k]], 1);
    }
  }
  __syncthreads();
  if (tid == 0) {
    int a = 0;
    for (int e = 0; e < NE; ++e) { off_s[e] = a; a += cnt_s[e]; }
    off_s[NE] = a;
  }
  __syncthreads();
  #pragma unroll
  for (int p = 0; p < 2; ++p) {
    const int t = tid + p * 1024;
    #pragma unroll
    for (int k = 0; k < TOPK; ++k) {
      int e = ids[p][k];
      int pos = off_s[e] + atomicAdd(&fill_s[e], 1);
      tok[pos] = t;
      slot_of[t*TOPK + k] = pos;
    }
  }
  if (tid <= NE) offsets_g[tid] = off_s[tid];
}

__global__ void k_xcast(const float* __restrict__ x, bf16* __restrict__ xb) {
  int i = blockIdx.x * blockDim.x + threadIdx.x;
  int base = i * 4;
  if (base >= NTOK * DM) return;
  float4 f = *(const float4*)(x + base);
  bf16x4 o;
  o[0] = (bf16)f.x; o[1] = (bf16)f.y; o[2] = (bf16)f.z; o[3] = (bf16)f.w;
  *(bf16x4*)(xb + base) = o;
}

// ---------------- grouped GEMM, 2-phase double-buffered ----------------
// A (bf16) staged via global_load_lds (linear LDS dest, pre-swizzled source
// col so the XOR-swizzled ds_read stays conflict-free). B (fp32) reg-staged
// (16 VGPRs), converted to bf16 after the MFMA cluster, ds_written swizzled.
// One barrier per K-tile; next tile's loads are in flight across the whole
// iteration. PASS2 is K-split (KSPLIT=2) for 2 blocks/CU; partial outputs.

template<int PASS, int KSPLIT>
__global__ __launch_bounds__(512, 4) void k_gemm(
    const float* __restrict__ W, const float* __restrict__ bias,
    const bf16* __restrict__ Asrc, const int* __restrict__ tok,
    const int* __restrict__ offsets,
    bf16* __restrict__ Hout, float* __restrict__ Oout)
{
  constexpr int KFULL = (PASS == 1) ? DM : DF;
  constexpr int KLOC  = KFULL / KSPLIT;
  constexpr int KT    = KLOC / BK;
  constexpr int NDIM  = (PASS == 1) ? DF : DM;

  const int e     = blockIdx.z;
  const int mtile = blockIdx.y;
  const int bx    = blockIdx.x;
  const int ntile = bx / KSPLIT;
  const int ks    = bx % KSPLIT;
  const int kbase = ks * KLOC;

  const int off = offsets[e];
  const int cnt = offsets[e+1] - off;
  if (mtile * BM >= cnt) return;
  const int rowcount = cnt - mtile * BM;
  const int tid = threadIdx.x;
  const int wave = tid >> 6, lane = tid & 63;

  __shared__ bf16 As[2][BM * BK];   // 2 x 24 KB
  __shared__ bf16 Bs[2][BN * BK];   // 2 x 16 KB

  // --- A staging: 3 chunks; per-lane pre-swizzled global src, uniform LDS base ---
  const bf16* aptr[3];
  uint32_t albase[3];
  #pragma unroll
  for (int c = 0; c < 3; ++c) {
    int r  = (c * 512 + tid) >> 3;        // tile row 0..191
    int u  = tid & 7;                     // 16B unit within row
    int rr = min(r, rowcount - 1);
    int srcrow;
    if (PASS == 1) srcrow = tok[off + mtile*BM + rr];
    else           srcrow = min(off + mtile*BM + rr, TOTSLOT - 1);
    int su = u ^ (r & 7);                 // pre-swizzled source unit
    aptr[c]   = Asrc + (size_t)srcrow * KFULL + kbase + su * 8;
    albase[c] = (uint32_t)((c*64 + wave*8) * BK * 2);   // row0 * 128 bytes
  }

  // --- B staging: row = tid>>2; lane-group covers 64B contiguous per load ---
  const int brow = tid >> 2, lg = tid & 3;
  const float* bptr = W + (size_t)e * NDIM * KFULL
                        + (size_t)(ntile*BN + brow) * KFULL + kbase;
  float4 bn[4];

  // --- wave / fragment geometry: 8 waves = 4(M) x 2(N), wave tile 48x64 ---
  const int wm = wave >> 1, wn = wave & 1;
  const int lrow = lane >> 4, lcol = lane & 15;

  f32x4 acc[3][4];
  #pragma unroll
  for (int i = 0; i < 3; ++i)
    #pragma unroll
    for (int j = 0; j < 4; ++j) acc[i][j] = (f32x4)(0.0f);

  // helpers ----------------------------------------------------------------
  auto stageA = [&](int kt, int b) {
    #pragma unroll
    for (int c = 0; c < 3; ++c)
      GLD_LDS16(aptr[c] + kt * BK, (char*)&As[b][0] + albase[c]);
  };
  auto loadB = [&](int kt) {
    #pragma unroll
    for (int q = 0; q < 4; ++q)
      bn[q] = *(const float4*)(bptr + kt*BK + (lg + q*4) * 4);
  };
  auto writeB = [&](int b) {
    #pragma unroll
    for (int q = 0; q < 4; ++q) {
      bf16x4 p;
      p[0] = (bf16)bn[q].x; p[1] = (bf16)bn[q].y;
      p[2] = (bf16)bn[q].z; p[3] = (bf16)bn[q].w;
      int s = lg + q*4;                       // 4-col group index 0..15
      int unit = s >> 1, half = s & 1;
      *(bf16x4*)((char*)&Bs[b][0] + brow*128 + ((unit ^ (brow & 7)) * 16) + half*8) = p;
    }
  };
  auto compute = [&](int b) {
    #pragma unroll
    for (int ksub = 0; ksub < 2; ++ksub) {
      const int uu = ksub*4 + lrow;
      bf16x8 af[3], bfr[4];
      #pragma unroll
      for (int i = 0; i < 3; ++i) {
        int m = wm*48 + i*16 + lcol;
        af[i] = *(const bf16x8*)(&As[b][m*BK + ((uu ^ (m & 7)) * 8)]);
      }
      #pragma unroll
      for (int j = 0; j < 4; ++j) {
        int n = wn*64 + j*16 + lcol;
        bfr[j] = *(const bf16x8*)(&Bs[b][n*BK + ((uu ^ (n & 7)) * 8)]);
      }
      #pragma unroll
      for (int i = 0; i < 3; ++i)
        #pragma unroll
        for (int j = 0; j < 4; ++j)
          acc[i][j] = __builtin_amdgcn_mfma_f32_16x16x32_bf16(af[i], bfr[j], acc[i][j], 0, 0, 0);
    }
  };

  // prologue: tile 0 synchronous; tile 1 in flight ------------------------
  stageA(0, 0);
  loadB(0);
  writeB(0);                     // vmcnt wait for bn happens here
  __syncthreads();               // drains A_lds(0); tile 0 ready
  if (KT > 1) { stageA(1, 1); loadB(1); }
  __builtin_amdgcn_sched_barrier(0);

  int cur = 0;
  #pragma unroll 1
  for (int kt = 0; kt < KT; ++kt) {
    compute(cur);                              // ds_read + MFMA on tile kt
    if (kt + 1 < KT) writeB(cur ^ 1);          // convert+write B(kt+1)
    __syncthreads();                           // tile kt+1 fully staged
    if (kt + 2 < KT) {
      stageA(kt + 2, cur);                     // buf cur just freed
      loadB(kt + 2);
      __builtin_amdgcn_sched_barrier(0);
    }
    cur ^= 1;
  }

  // --- epilogue. C/D layout: col = lane&15, row = (lane>>4)*4 + reg ---
  const int slotbase = off + mtile * BM;
  #pragma unroll
  for (int i = 0; i < 3; ++i) {
    const int rbase = wm*48 + i*16 + lrow*4;
    #pragma unroll
    for (int j = 0; j < 4; ++j) {
      const int gcol = ntile*BN + wn*64 + j*16 + lcol;
      const float bv = (PASS == 2 && ks != 0) ? 0.0f : bias[(size_t)e * NDIM + gcol];
      #pragma unroll
      for (int q = 0; q < 4; ++q) {
        const int r = rbase + q;
        if (r < rowcount) {
          float h = acc[i][j][q] + bv;
          if (PASS == 1) {
            float s = h / (1.0f + __expf(-h));      // silu
            Hout[(size_t)(slotbase + r) * DF + gcol] = (bf16)s;
          } else {
            Oout[(size_t)ks * TOTSLOT * DM + (size_t)(slotbase + r) * DM + gcol] = h;
          }
        }
      }
    }
  }
}

// ---------------- combine (deterministic, sums K-split partials) ----------------

__global__ void k_combine(const float* __restrict__ O, const float* __restrict__ top_w,
                          const int* __restrict__ slot_of, float* __restrict__ out) {
  int i = blockIdx.x * blockDim.x + threadIdx.x;
  if (i >= NTOK * DM / 4) return;
  int t  = i / (DM / 4);
  int d4 = (i % (DM / 4)) * 4;
  float4 s = {0.f, 0.f, 0.f, 0.f};
  #pragma unroll
  for (int k = 0; k < TOPK; ++k) {
    float w = top_w[t*TOPK + k];
    int  sl = slot_of[t*TOPK + k];
    float4 o0 = *(const float4*)(O + (size_t)sl * DM + d4);
    float4 o1 = *(const float4*)(O + (size_t)TOTSLOT * DM + (size_t)sl * DM + d4);
    s.x += w * (o0.x + o1.x); s.y += w * (o0.y + o1.y);
    s.z += w * (o0.z + o1.z); s.w += w * (o0.w + o1.w);
  }
  *(float4*)(out + (size_t)t * DM + d4) = s;
}

// ---------------- launch ----------------

extern "C" void kernel_launch(void* const* d_in, const int* in_sizes, int n_in,
                              void* d_out, int out_size, void* d_ws, size_t ws_size,
                              hipStream_t stream) {
  const float* x        = (const float*)d_in[0];
  const float* hw       = (const float*)d_in[1];
  const float* W_in     = (const float*)d_in[2];
  const float* bias_in  = (const float*)d_in[3];
  const float* W_out    = (const float*)d_in[4];
  const float* bias_out = (const float*)d_in[5];
  float* out = (float*)d_out;

  char* ws = (char*)d_ws;
  int*   offsets = (int*)  (ws + 0);                     // 65 ints
  float* top_w   = (float*)(ws + 1024);                  // 32 KB
  int*   slot_of = (int*)  (ws + 1024 + 32768);          // 32 KB
  int*   tok     = (int*)  (ws + 1024 + 2*32768);        // 32 KB
  bf16*  xb      = (bf16*) (ws + 1024 + 3*32768);        // 2 MB
  size_t o_xb_end = 1024 + 3*32768 + (size_t)NTOK*DM*2;
  bf16*  H       = (bf16*) (ws + o_xb_end);              // 32 MB
  size_t o_H_end  = o_xb_end + (size_t)TOTSLOT*DF*2;
  float* O       = (float*)(ws + o_H_end);               // 2 x 16 MB (K-split partials)

  k_xcast  <<<(NTOK*DM/4)/256, 256, 0, stream>>>(x, xb);
  k_routing<<<1, 1024, 0, stream>>>(hw, top_w, tok, slot_of, offsets);

  dim3 g1(DF/BN, MT_MAX, NE);       // (16, 11, 64)
  k_gemm<1,1><<<g1, 512, 0, stream>>>(W_in, bias_in, xb, tok, offsets, H, nullptr);
  dim3 g2((DM/BN)*2, MT_MAX, NE);   // (8, 11, 64), ksplit=2
  k_gemm<2,2><<<g2, 512, 0, stream>>>(W_out, bias_out, H, nullptr, offsets, nullptr, O);

  k_combine<<<(NTOK*DM/4)/256, 256, 0, stream>>>(O, top_w, slot_of, out);
}